// Round 7
// baseline (183.216 us; speedup 1.0000x reference)
//
#include <hip/hip_runtime.h>

// Problem dims (hard-coded in reference)
#define DD   768
#define NN   512
#define MM   512

#define PRE_K 2.88539008177792681472f   // 2*log2(e)

typedef _Float16 h8 __attribute__((ext_vector_type(8)));  // 8 f16 (4 VGPRs)
typedef __attribute__((ext_vector_type(4))) float f32x4;  // MFMA C/D

__device__ __forceinline__ float fexp(float x) { return __builtin_amdgcn_exp2f(x); }
__device__ __forceinline__ float frcp(float x) { return __builtin_amdgcn_rcpf(x); }
// tanh(x) = 1 - 2/(1 + e^{2x}); saturates correctly via exp2->inf/0 + rcp.
__device__ __forceinline__ float fast_tanh(float x) {
  return 1.0f - 2.0f * frcp(fexp(PRE_K * x) + 1.0f);
}

// fp32 -> f16 hi/lo split (pair covers ~21 mantissa bits; 40x tighter than bf16)
__device__ __forceinline__ void splitf(float x, ushort& h, ushort& l) {
  const _Float16 hh = (_Float16)x;
  const _Float16 ll = (_Float16)(x - (float)hh);
  h = __builtin_bit_cast(unsigned short, hh);
  l = __builtin_bit_cast(unsigned short, ll);
}

// ---- prep A: elementwise f16 hi/lo split of text, visual, W3 ([row][k]) ----
__global__ __launch_bounds__(256) void convert_kernel(
    const float* __restrict__ text, const float* __restrict__ visual,
    const float* __restrict__ W3,
    ushort* __restrict__ th, ushort* __restrict__ tl,
    ushort* __restrict__ vh, ushort* __restrict__ vl,
    ushort* __restrict__ w3h, ushort* __restrict__ w3l)
{
  const int z = blockIdx.z;
  const float* src = (z == 0) ? text : (z == 1) ? visual : W3;
  ushort* dh = (z == 0) ? th : (z == 1) ? vh : w3h;
  ushort* dl = (z == 0) ? tl : (z == 1) ? vl : w3l;
  const int count = ((z == 2) ? DD * DD : NN * DD) / 4;
  const int i = blockIdx.x * 256 + threadIdx.x;
  if (i >= count) return;
  const float4 v = *(const float4*)&src[(size_t)i * 4];
  ushort4 h, l;
  splitf(v.x, h.x, l.x); splitf(v.y, h.y, l.y);
  splitf(v.z, h.z, l.z); splitf(v.w, h.w, l.w);
  *(ushort4*)&dh[(size_t)i * 4] = h;
  *(ushort4*)&dl[(size_t)i * 4] = l;
}

// ---- prep B: transpose + split W1, W2 -> [j][k] f16 hi/lo ------------------
__global__ __launch_bounds__(256) void transpose_kernel(
    const float* __restrict__ W1, const float* __restrict__ W2,
    ushort* __restrict__ w1th, ushort* __restrict__ w1tl,
    ushort* __restrict__ w2th, ushort* __restrict__ w2tl)
{
  __shared__ float Lt[32][33];
  const float* W = blockIdx.z ? W2 : W1;
  ushort* oh = blockIdx.z ? w2th : w1th;
  ushort* ol = blockIdx.z ? w2tl : w1tl;
  const int k0 = blockIdx.y * 32, j0 = blockIdx.x * 32;
  const int t = threadIdx.x;
  {
    const int k = t >> 3, j4 = (t & 7) * 4;
    const float4 v = *(const float4*)&W[(size_t)(k0 + k) * DD + j0 + j4];
    Lt[j4 + 0][k] = v.x; Lt[j4 + 1][k] = v.y;
    Lt[j4 + 2][k] = v.z; Lt[j4 + 3][k] = v.w;
  }
  __syncthreads();
  {
    const int j = t >> 3, k4 = (t & 7) * 4;
    ushort4 h, l;
    splitf(Lt[j][k4 + 0], h.x, l.x); splitf(Lt[j][k4 + 1], h.y, l.y);
    splitf(Lt[j][k4 + 2], h.z, l.z); splitf(Lt[j][k4 + 3], h.w, l.w);
    *(ushort4*)&oh[(size_t)(j0 + j) * DD + k0 + k4] = h;
    *(ushort4*)&ol[(size_t)(j0 + j) * DD + k0 + k4] = l;
  }
}

// ---- MFMA GEMM 1 -----------------------------------------------------------
// z=0: A=text@W1 -> Ah/Al(f16)  z=1: kw2t=PRE_K*text@W2  z=2: kw3v=PRE_K*visual@W3^T
// f16 split: hi*hi + hi*lo + lo*hi (lo*lo ~ 2^-22, dropped).
// ONE 16x16 tile per wave, full K: grid (48,8,3)=1152 blocks = 4.5 waves/SIMD
// (R6 lesson: 288 blocks = 1.1 w/SIMD left MFMA pipe 97% idle on load latency).
// All 4 waves of a block share j0 -> B frags L1-resident after first wave.
__global__ __launch_bounds__(256) void mfma1_kernel(
    const ushort* __restrict__ th, const ushort* __restrict__ tl,
    const ushort* __restrict__ vh, const ushort* __restrict__ vl,
    const ushort* __restrict__ w1th, const ushort* __restrict__ w1tl,
    const ushort* __restrict__ w2th, const ushort* __restrict__ w2tl,
    const ushort* __restrict__ w3h, const ushort* __restrict__ w3l,
    ushort* __restrict__ Ah, ushort* __restrict__ Al,
    float* __restrict__ kw2t, float* __restrict__ kw3v)
{
  const int z  = blockIdx.z;
  const int j0 = blockIdx.x * 16;   // out col
  const int i0 = blockIdx.y * 64;   // out row block (4 waves x 16)
  const ushort *Arh, *Arl, *Brh, *Brl;
  if (z == 0)      { Arh = th; Arl = tl; Brh = w1th; Brl = w1tl; }
  else if (z == 1) { Arh = th; Arl = tl; Brh = w2th; Brl = w2tl; }
  else             { Arh = vh; Arl = vl; Brh = w3h;  Brl = w3l;  }

  const int lane = threadIdx.x & 63;
  const int wave = threadIdx.x >> 6;
  const int r15  = lane & 15;
  const int quad = lane >> 4;

  const ushort* aph = Arh + (size_t)(i0 + wave * 16 + r15) * DD + quad * 8;
  const ushort* apl = Arl + (size_t)(i0 + wave * 16 + r15) * DD + quad * 8;
  const ushort* bph = Brh + (size_t)(j0 + r15) * DD + quad * 8;
  const ushort* bpl = Brl + (size_t)(j0 + r15) * DD + quad * 8;

  f32x4 acc = (f32x4){0.f, 0.f, 0.f, 0.f};
  for (int ks = 0; ks < DD; ks += 32) {
    const h8 a_h = *(const h8*)(aph + ks);
    const h8 a_l = *(const h8*)(apl + ks);
    const h8 b_h = *(const h8*)(bph + ks);
    const h8 b_l = *(const h8*)(bpl + ks);
    acc = __builtin_amdgcn_mfma_f32_16x16x32_f16(a_h, b_h, acc, 0, 0, 0);
    acc = __builtin_amdgcn_mfma_f32_16x16x32_f16(a_h, b_l, acc, 0, 0, 0);
    acc = __builtin_amdgcn_mfma_f32_16x16x32_f16(a_l, b_h, acc, 0, 0, 0);
  }

  // C/D layout: col = lane&15, row = quad*4 + reg
  if (z == 0) {
    #pragma unroll
    for (int r = 0; r < 4; ++r) {
      const size_t o = (size_t)(i0 + wave * 16 + quad * 4 + r) * DD + j0 + r15;
      splitf(acc[r], Ah[o], Al[o]);
    }
  } else {
    float* Out = (z == 1) ? kw2t : kw3v;
    #pragma unroll
    for (int r = 0; r < 4; ++r)
      Out[(size_t)(i0 + wave * 16 + quad * 4 + r) * DD + j0 + r15] = acc[r] * PRE_K;
  }
}

// ---- MFMA GEMM 2: Q[z] = A @ visual^T over K half z  (grid (32,8,2)) -------
__global__ __launch_bounds__(256) void mfma2_kernel(
    const ushort* __restrict__ Ah, const ushort* __restrict__ Al,
    const ushort* __restrict__ vh, const ushort* __restrict__ vl,
    float* __restrict__ Q)
{
  const int z  = blockIdx.z;
  const int k0 = z * (DD / 2);
  const int j0 = blockIdx.x * 16;
  const int i0 = blockIdx.y * 64;

  const int lane = threadIdx.x & 63;
  const int wave = threadIdx.x >> 6;
  const int r15  = lane & 15;
  const int quad = lane >> 4;

  const ushort* aph = Ah + (size_t)(i0 + wave * 16 + r15) * DD + k0 + quad * 8;
  const ushort* apl = Al + (size_t)(i0 + wave * 16 + r15) * DD + k0 + quad * 8;
  const ushort* bph = vh + (size_t)(j0 + r15) * DD + k0 + quad * 8;
  const ushort* bpl = vl + (size_t)(j0 + r15) * DD + k0 + quad * 8;

  f32x4 acc = (f32x4){0.f, 0.f, 0.f, 0.f};
  for (int ks = 0; ks < DD / 2; ks += 32) {
    const h8 a_h = *(const h8*)(aph + ks);
    const h8 a_l = *(const h8*)(apl + ks);
    const h8 b_h = *(const h8*)(bph + ks);
    const h8 b_l = *(const h8*)(bpl + ks);
    acc = __builtin_amdgcn_mfma_f32_16x16x32_f16(a_h, b_h, acc, 0, 0, 0);
    acc = __builtin_amdgcn_mfma_f32_16x16x32_f16(a_h, b_l, acc, 0, 0, 0);
    acc = __builtin_amdgcn_mfma_f32_16x16x32_f16(a_l, b_h, acc, 0, 0, 0);
  }

  float* Out = Q + (size_t)z * NN * MM;
  #pragma unroll
  for (int r = 0; r < 4; ++r)
    Out[(size_t)(i0 + wave * 16 + quad * 4 + r) * MM + j0 + r15] = acc[r];
}

// Ct = tanh(Q0 + Q1)
__global__ __launch_bounds__(256) void reducec_kernel(
    const float* __restrict__ Q, float* __restrict__ Ct)
{
  const size_t i = ((size_t)blockIdx.x * 256 + threadIdx.x) * 4;
  const float4 q0 = *(const float4*)&Q[i];
  const float4 q1 = *(const float4*)&Q[(size_t)NN * MM + i];
  float4 o;
  o.x = fast_tanh(q0.x + q1.x); o.y = fast_tanh(q0.y + q1.y);
  o.z = fast_tanh(q0.z + q1.z); o.w = fast_tanh(q0.w + q1.w);
  *(float4*)&Ct[i] = o;
}

// T[n] = sum_d text[n,d]
__global__ __launch_bounds__(64) void tsum_kernel(
    const float* __restrict__ text, float* __restrict__ T)
{
  const int n = blockIdx.x;
  const int lane = threadIdx.x;
  float s = 0.f;
  #pragma unroll
  for (int i = 0; i < DD / 64; ++i) s += text[n * DD + lane + i * 64];
  #pragma unroll
  for (int off = 32; off; off >>= 1) s += __shfl_down(s, off);
  if (lane == 0) T[n] = s;
}

// ---- main fused kernel (d-split x3: 1536 blocks = 6 waves/SIMD) ------------
// Spart[z][n,m] = sum_{d in third z} text[n,d]*rcp(1+exp2(kw2t[n,d]+kw3v[m,d]*Ct[n,m]))
#define DCH    64
#define DRANGE 256
#define MLDW   68

__global__ __launch_bounds__(256) void main_kernel(
    const float* __restrict__ text, const float* __restrict__ kw2t,
    const float* __restrict__ kw3v, const float* __restrict__ Ct,
    float* __restrict__ Spart)
{
  __shared__ float ts[16][MLDW];
  __shared__ float w2s[16][MLDW];
  __shared__ float w3s[32][MLDW];

  const int tid = threadIdx.x;
  const int nl = tid >> 4;
  const int ml = tid & 15;
  const int n0 = blockIdx.y * 16;
  const int m0 = blockIdx.x * 32;
  const int z  = blockIdx.z;
  const int n  = n0 + nl;
  const int mA = m0 + ml, mB = mA + 16;
  const int dbase = z * DRANGE;

  const float cA = Ct[(size_t)n * MM + mA];
  const float cB = Ct[(size_t)n * MM + mB];

  float4 aA = {0.f, 0.f, 0.f, 0.f};
  float4 aB = {0.f, 0.f, 0.f, 0.f};

  const int srow = tid >> 4;
  const int sc4  = (tid & 15) << 2;

  for (int dc = 0; dc < DRANGE; dc += DCH) {
    const int d0 = dbase + dc;
    *(float4*)&ts[srow][sc4]       = *(const float4*)&text[(size_t)(n0 + srow) * DD + d0 + sc4];
    *(float4*)&w2s[srow][sc4]      = *(const float4*)&kw2t[(size_t)(n0 + srow) * DD + d0 + sc4];
    *(float4*)&w3s[srow][sc4]      = *(const float4*)&kw3v[(size_t)(m0 + srow) * DD + d0 + sc4];
    *(float4*)&w3s[srow + 16][sc4] = *(const float4*)&kw3v[(size_t)(m0 + 16 + srow) * DD + d0 + sc4];
    __syncthreads();

    #pragma unroll 4
    for (int j = 0; j < DCH; j += 4) {
      const float4 tv  = *(const float4*)&ts[nl][j];
      const float4 w2  = *(const float4*)&w2s[nl][j];
      const float4 w3A = *(const float4*)&w3s[ml][j];
      const float4 w3B = *(const float4*)&w3s[ml + 16][j];
      aA.x = fmaf(tv.x, frcp(fexp(fmaf(w3A.x, cA, w2.x)) + 1.0f), aA.x);
      aA.y = fmaf(tv.y, frcp(fexp(fmaf(w3A.y, cA, w2.y)) + 1.0f), aA.y);
      aA.z = fmaf(tv.z, frcp(fexp(fmaf(w3A.z, cA, w2.z)) + 1.0f), aA.z);
      aA.w = fmaf(tv.w, frcp(fexp(fmaf(w3A.w, cA, w2.w)) + 1.0f), aA.w);
      aB.x = fmaf(tv.x, frcp(fexp(fmaf(w3B.x, cB, w2.x)) + 1.0f), aB.x);
      aB.y = fmaf(tv.y, frcp(fexp(fmaf(w3B.y, cB, w2.y)) + 1.0f), aB.y);
      aB.z = fmaf(tv.z, frcp(fexp(fmaf(w3B.z, cB, w2.z)) + 1.0f), aB.z);
      aB.w = fmaf(tv.w, frcp(fexp(fmaf(w3B.w, cB, w2.w)) + 1.0f), aB.w);
    }
    __syncthreads();
  }

  float* Sp = Spart + (size_t)z * NN * MM + (size_t)n * MM;
  Sp[mA] = (aA.x + aA.y) + (aA.z + aA.w);
  Sp[mB] = (aB.x + aB.y) + (aB.z + aB.w);
}

// out[n,m] = T[n] - 2*(S0+S1+S2)
__global__ __launch_bounds__(256) void combine_kernel(
    const float* __restrict__ Spart, const float* __restrict__ T,
    float* __restrict__ out)
{
  const size_t i = ((size_t)blockIdx.x * 256 + threadIdx.x) * 4;
  const size_t S = (size_t)NN * MM;
  const int n = (int)(i >> 9);
  const float Tn = T[n];
  const float4 s0 = *(const float4*)&Spart[i];
  const float4 s1 = *(const float4*)&Spart[S + i];
  const float4 s2 = *(const float4*)&Spart[2 * S + i];
  float4 o;
  o.x = Tn - 2.0f * (s0.x + s1.x + s2.x);
  o.y = Tn - 2.0f * (s0.y + s1.y + s2.y);
  o.z = Tn - 2.0f * (s0.z + s1.z + s2.z);
  o.w = Tn - 2.0f * (s0.w + s1.w + s2.w);
  *(float4*)&out[i] = o;
}

// ---- launcher --------------------------------------------------------------
extern "C" void kernel_launch(void* const* d_in, const int* in_sizes, int n_in,
                              void* d_out, int out_size, void* d_ws, size_t ws_size,
                              hipStream_t stream) {
  const float* text   = (const float*)d_in[0];
  const float* visual = (const float*)d_in[1];
  const float* W1     = (const float*)d_in[2];
  const float* W2     = (const float*)d_in[3];
  const float* W3     = (const float*)d_in[4];
  float* out = (float*)d_out;

  // Workspace byte layout (peak 14.25 MB <= 15.2 MB proven in R3):
  //   th/tl/vh/vl: f16 hi/lo of text, visual   (4 x 768 KB)
  //   w1t/w2t h,l: f16 hi/lo of W1^T,W2^T [j][k] (4 x 1.125 MB)
  //   w3 h/l     : f16 hi/lo of W3 [j][k]        (2 x 1.125 MB)
  //   Ah/Al      : f16 hi/lo of A               (2 x 768 KB)
  //   kw2t/kw3v  : fp32                          (2 x 1.5 MB)
  //   T          : fp32[512]
  // Overlays (stream-serial, source dead before overwrite):
  //   Q  (2 MB) -> w1th/w1tl   (dead after mfma1)
  //   Ct (1 MB) -> w2th        (dead after mfma1)
  //   Spart (3 MB) -> w2tl+w3h+w3l (dead after mfma1)
  char* base = (char*)d_ws;
  ushort* th   = (ushort*)(base);
  ushort* tl   = (ushort*)(base + 786432);
  ushort* vh   = (ushort*)(base + 1572864);
  ushort* vl   = (ushort*)(base + 2359296);
  ushort* w1th = (ushort*)(base + 3145728);
  ushort* w1tl = (ushort*)(base + 4325376);
  ushort* w2th = (ushort*)(base + 5505024);
  ushort* w2tl = (ushort*)(base + 6684672);
  ushort* w3h  = (ushort*)(base + 7864320);
  ushort* w3l  = (ushort*)(base + 9043968);
  ushort* Ah   = (ushort*)(base + 10223616);
  ushort* Al   = (ushort*)(base + 11010048);
  float*  kw2t = (float*) (base + 11796480);
  float*  kw3v = (float*) (base + 13369344);
  float*  T    = (float*) (base + 14942208);
  float*  Q     = (float*)(base + 3145728);   // 2 MB over w1t
  float*  Ct    = (float*)(base + 5505024);   // 1 MB over w2th
  float*  Spart = (float*)(base + 6684672);   // 3 MB over w2tl+w3

  hipLaunchKernelGGL(tsum_kernel, dim3(NN), dim3(64), 0, stream, text, T);
  hipLaunchKernelGGL(convert_kernel, dim3(DD * DD / 1024, 1, 3), dim3(256), 0, stream,
                     text, visual, W3, th, tl, vh, vl, w3h, w3l);
  hipLaunchKernelGGL(transpose_kernel, dim3(DD / 32, DD / 32, 2), dim3(256), 0, stream,
                     W1, W2, w1th, w1tl, w2th, w2tl);
  hipLaunchKernelGGL(mfma1_kernel, dim3(DD / 16, NN / 64, 3), dim3(256), 0, stream,
                     th, tl, vh, vl, w1th, w1tl, w2th, w2tl, w3h, w3l,
                     Ah, Al, kw2t, kw3v);
  hipLaunchKernelGGL(mfma2_kernel, dim3(MM / 16, NN / 64, 2), dim3(256), 0, stream,
                     Ah, Al, vh, vl, Q);
  hipLaunchKernelGGL(reducec_kernel, dim3(NN * MM / 1024), dim3(256), 0, stream,
                     Q, Ct);
  hipLaunchKernelGGL(main_kernel, dim3(MM / 32, NN / 16, 3), dim3(256), 0, stream,
                     text, kw2t, kw3v, Ct, Spart);
  hipLaunchKernelGGL(combine_kernel, dim3(NN * MM / 1024), dim3(256), 0, stream,
                     Spart, T, out);
}

// Round 8
// 146.727 us; speedup vs baseline: 1.2487x; 1.2487x over previous
//
#include <hip/hip_runtime.h>

// Problem dims (hard-coded in reference)
#define DD   768
#define NN   512
#define MM   512

#define PRE_K 2.88539008177792681472f   // 2*log2(e)

typedef _Float16 h8 __attribute__((ext_vector_type(8)));  // 8 f16 (4 VGPRs)
typedef __attribute__((ext_vector_type(4))) float f32x4;  // MFMA C/D

__device__ __forceinline__ float fexp(float x) { return __builtin_amdgcn_exp2f(x); }
__device__ __forceinline__ float frcp(float x) { return __builtin_amdgcn_rcpf(x); }
// tanh(x) = 1 - 2/(1 + e^{2x}); saturates correctly via exp2->inf/0 + rcp.
__device__ __forceinline__ float fast_tanh(float x) {
  return 1.0f - 2.0f * frcp(fexp(PRE_K * x) + 1.0f);
}

// fp32 -> f16 hi/lo split (pair covers ~21 mantissa bits)
__device__ __forceinline__ void splitf(float x, ushort& h, ushort& l) {
  const _Float16 hh = (_Float16)x;
  const _Float16 ll = (_Float16)(x - (float)hh);
  h = __builtin_bit_cast(unsigned short, hh);
  l = __builtin_bit_cast(unsigned short, ll);
}

// ---- prep A: elementwise f16 hi/lo split of text, visual, W3 ([row][k]) ----
__global__ __launch_bounds__(256) void convert_kernel(
    const float* __restrict__ text, const float* __restrict__ visual,
    const float* __restrict__ W3,
    ushort* __restrict__ th, ushort* __restrict__ tl,
    ushort* __restrict__ vh, ushort* __restrict__ vl,
    ushort* __restrict__ w3h, ushort* __restrict__ w3l)
{
  const int z = blockIdx.z;
  const float* src = (z == 0) ? text : (z == 1) ? visual : W3;
  ushort* dh = (z == 0) ? th : (z == 1) ? vh : w3h;
  ushort* dl = (z == 0) ? tl : (z == 1) ? vl : w3l;
  const int count = ((z == 2) ? DD * DD : NN * DD) / 4;
  const int i = blockIdx.x * 256 + threadIdx.x;
  if (i >= count) return;
  const float4 v = *(const float4*)&src[(size_t)i * 4];
  ushort4 h, l;
  splitf(v.x, h.x, l.x); splitf(v.y, h.y, l.y);
  splitf(v.z, h.z, l.z); splitf(v.w, h.w, l.w);
  *(ushort4*)&dh[(size_t)i * 4] = h;
  *(ushort4*)&dl[(size_t)i * 4] = l;
}

// ---- prep B: transpose + split W1, W2 -> [j][k] f16 hi/lo ------------------
__global__ __launch_bounds__(256) void transpose_kernel(
    const float* __restrict__ W1, const float* __restrict__ W2,
    ushort* __restrict__ w1th, ushort* __restrict__ w1tl,
    ushort* __restrict__ w2th, ushort* __restrict__ w2tl)
{
  __shared__ float Lt[32][33];
  const float* W = blockIdx.z ? W2 : W1;
  ushort* oh = blockIdx.z ? w2th : w1th;
  ushort* ol = blockIdx.z ? w2tl : w1tl;
  const int k0 = blockIdx.y * 32, j0 = blockIdx.x * 32;
  const int t = threadIdx.x;
  {
    const int k = t >> 3, j4 = (t & 7) * 4;
    const float4 v = *(const float4*)&W[(size_t)(k0 + k) * DD + j0 + j4];
    Lt[j4 + 0][k] = v.x; Lt[j4 + 1][k] = v.y;
    Lt[j4 + 2][k] = v.z; Lt[j4 + 3][k] = v.w;
  }
  __syncthreads();
  {
    const int j = t >> 3, k4 = (t & 7) * 4;
    ushort4 h, l;
    splitf(Lt[j][k4 + 0], h.x, l.x); splitf(Lt[j][k4 + 1], h.y, l.y);
    splitf(Lt[j][k4 + 2], h.z, l.z); splitf(Lt[j][k4 + 3], h.w, l.w);
    *(ushort4*)&oh[(size_t)(j0 + j) * DD + k0 + k4] = h;
    *(ushort4*)&ol[(size_t)(j0 + j) * DD + k0 + k4] = l;
  }
}

// ---- staged-LDS MFMA GEMM core (m97 pattern, scaled down) ------------------
// Block = 256 thr (4 waves), 64x64 out tile, BK=32, double-buffered LDS.
// R7 lesson: frag-direct global loads = pointer-chase (~2.9k cyc/iter,
// MfmaUtil 3.4% regardless of occupancy). Canonical fix: coalesced
// global->LDS staging + ds_read_b128 frags + register prefetch.
// Wave w: rows 16w..16w+15, 4 col-tiles -> 4 independent MFMA chains.
#define BK   32
#define LROW 40   // padded LDS row stride (f16): 2-way banks, 16B-aligned

__device__ __forceinline__ void gemm_core(
    const ushort* __restrict__ Ahg, const ushort* __restrict__ Alg,
    const ushort* __restrict__ Bhg, const ushort* __restrict__ Blg,
    int i0, int j0, int k0, int nsteps, f32x4* acc)
{
  __shared__ ushort As[2][2][64 * LROW];   // [buf][hi/lo][row*LROW+k]
  __shared__ ushort Bs[2][2][64 * LROW];

  const int tid  = threadIdx.x;
  const int row  = tid >> 2;            // 0..63 staging row
  const int ks8  = (tid & 3) * 8;       // 0,8,16,24 (f16)
  const size_t ga = (size_t)(i0 + row) * DD + k0 + ks8;
  const size_t gb = (size_t)(j0 + row) * DD + k0 + ks8;
  const int ldsw = row * LROW + ks8;

  const int lane = tid & 63, wave = tid >> 6;
  const int r15 = lane & 15, quad = lane >> 4;
  const int fa = (wave * 16 + r15) * LROW + quad * 8;   // A frag offset
  const int fb = r15 * LROW + quad * 8;                 // B frag base

  // prefetch step 0
  h8 pah = *(const h8*)(Ahg + ga);
  h8 pal = *(const h8*)(Alg + ga);
  h8 pbh = *(const h8*)(Bhg + gb);
  h8 pbl = *(const h8*)(Blg + gb);

  int p = 0;
  *(h8*)&As[0][0][ldsw] = pah; *(h8*)&As[0][1][ldsw] = pal;
  *(h8*)&Bs[0][0][ldsw] = pbh; *(h8*)&Bs[0][1][ldsw] = pbl;
  __syncthreads();

  for (int s = 0; s < nsteps; ++s) {
    const bool more = (s + 1 < nsteps);
    if (more) {  // issue next chunk's globals; MFMA below hides latency
      pah = *(const h8*)(Ahg + ga + (s + 1) * BK);
      pal = *(const h8*)(Alg + ga + (s + 1) * BK);
      pbh = *(const h8*)(Bhg + gb + (s + 1) * BK);
      pbl = *(const h8*)(Blg + gb + (s + 1) * BK);
    }
    const h8 a_h = *(const h8*)&As[p][0][fa];
    const h8 a_l = *(const h8*)&As[p][1][fa];
    h8 b_h[4], b_l[4];
    #pragma unroll
    for (int c = 0; c < 4; ++c) {
      b_h[c] = *(const h8*)&Bs[p][0][fb + c * 16 * LROW];
      b_l[c] = *(const h8*)&Bs[p][1][fb + c * 16 * LROW];
    }
    #pragma unroll
    for (int c = 0; c < 4; ++c)
      acc[c] = __builtin_amdgcn_mfma_f32_16x16x32_f16(a_h, b_h[c], acc[c], 0, 0, 0);
    #pragma unroll
    for (int c = 0; c < 4; ++c)
      acc[c] = __builtin_amdgcn_mfma_f32_16x16x32_f16(a_h, b_l[c], acc[c], 0, 0, 0);
    #pragma unroll
    for (int c = 0; c < 4; ++c)
      acc[c] = __builtin_amdgcn_mfma_f32_16x16x32_f16(a_l, b_h[c], acc[c], 0, 0, 0);
    if (more) {
      const int q = p ^ 1;
      *(h8*)&As[q][0][ldsw] = pah; *(h8*)&As[q][1][ldsw] = pal;
      *(h8*)&Bs[q][0][ldsw] = pbh; *(h8*)&Bs[q][1][ldsw] = pbl;
    }
    __syncthreads();
    p ^= 1;
  }
}

// z=0: A=text@W1 -> Ah/Al(f16)  z=1: kw2t=PRE_K*text@W2  z=2: kw3v=PRE_K*visual@W3^T
// grid (12, 8, 3) = 288 blocks, full K.
__global__ __launch_bounds__(256) void mfma1_kernel(
    const ushort* __restrict__ th, const ushort* __restrict__ tl,
    const ushort* __restrict__ vh, const ushort* __restrict__ vl,
    const ushort* __restrict__ w1th, const ushort* __restrict__ w1tl,
    const ushort* __restrict__ w2th, const ushort* __restrict__ w2tl,
    const ushort* __restrict__ w3h, const ushort* __restrict__ w3l,
    ushort* __restrict__ Ah, ushort* __restrict__ Al,
    float* __restrict__ kw2t, float* __restrict__ kw3v)
{
  const int z  = blockIdx.z;
  const int j0 = blockIdx.x * 64;
  const int i0 = blockIdx.y * 64;
  const ushort *Arh, *Arl, *Brh, *Brl;
  if (z == 0)      { Arh = th; Arl = tl; Brh = w1th; Brl = w1tl; }
  else if (z == 1) { Arh = th; Arl = tl; Brh = w2th; Brl = w2tl; }
  else             { Arh = vh; Arl = vl; Brh = w3h;  Brl = w3l;  }

  f32x4 acc[4];
  #pragma unroll
  for (int c = 0; c < 4; ++c) acc[c] = (f32x4){0.f, 0.f, 0.f, 0.f};
  gemm_core(Arh, Arl, Brh, Brl, i0, j0, 0, DD / BK, acc);

  const int lane = threadIdx.x & 63, wave = threadIdx.x >> 6;
  const int r15 = lane & 15, quad = lane >> 4;
  // C/D layout: col=lane&15 (B row j), row=quad*4+reg (A row i)
  if (z == 0) {
    #pragma unroll
    for (int c = 0; c < 4; ++c)
      #pragma unroll
      for (int r = 0; r < 4; ++r) {
        const size_t o = (size_t)(i0 + wave * 16 + quad * 4 + r) * DD + j0 + c * 16 + r15;
        splitf(acc[c][r], Ah[o], Al[o]);
      }
  } else {
    float* Out = (z == 1) ? kw2t : kw3v;
    #pragma unroll
    for (int c = 0; c < 4; ++c)
      #pragma unroll
      for (int r = 0; r < 4; ++r)
        Out[(size_t)(i0 + wave * 16 + quad * 4 + r) * DD + j0 + c * 16 + r15] =
            acc[c][r] * PRE_K;
  }
}

// Q[z] = A @ visual^T over K half z.  grid (8, 8, 2) = 128 blocks.
__global__ __launch_bounds__(256) void mfma2_kernel(
    const ushort* __restrict__ Ah, const ushort* __restrict__ Al,
    const ushort* __restrict__ vh, const ushort* __restrict__ vl,
    float* __restrict__ Q)
{
  const int z  = blockIdx.z;
  const int j0 = blockIdx.x * 64;
  const int i0 = blockIdx.y * 64;

  f32x4 acc[4];
  #pragma unroll
  for (int c = 0; c < 4; ++c) acc[c] = (f32x4){0.f, 0.f, 0.f, 0.f};
  gemm_core(Ah, Al, vh, vl, i0, j0, z * (DD / 2), (DD / 2) / BK, acc);

  const int lane = threadIdx.x & 63, wave = threadIdx.x >> 6;
  const int r15 = lane & 15, quad = lane >> 4;
  float* Out = Q + (size_t)z * NN * MM;
  #pragma unroll
  for (int c = 0; c < 4; ++c)
    #pragma unroll
    for (int r = 0; r < 4; ++r)
      Out[(size_t)(i0 + wave * 16 + quad * 4 + r) * MM + j0 + c * 16 + r15] = acc[c][r];
}

// Ct = tanh(Q0 + Q1)
__global__ __launch_bounds__(256) void reducec_kernel(
    const float* __restrict__ Q, float* __restrict__ Ct)
{
  const size_t i = ((size_t)blockIdx.x * 256 + threadIdx.x) * 4;
  const float4 q0 = *(const float4*)&Q[i];
  const float4 q1 = *(const float4*)&Q[(size_t)NN * MM + i];
  float4 o;
  o.x = fast_tanh(q0.x + q1.x); o.y = fast_tanh(q0.y + q1.y);
  o.z = fast_tanh(q0.z + q1.z); o.w = fast_tanh(q0.w + q1.w);
  *(float4*)&Ct[i] = o;
}

// T[n] = sum_d text[n,d]
__global__ __launch_bounds__(64) void tsum_kernel(
    const float* __restrict__ text, float* __restrict__ T)
{
  const int n = blockIdx.x;
  const int lane = threadIdx.x;
  float s = 0.f;
  #pragma unroll
  for (int i = 0; i < DD / 64; ++i) s += text[n * DD + lane + i * 64];
  #pragma unroll
  for (int off = 32; off; off >>= 1) s += __shfl_down(s, off);
  if (lane == 0) T[n] = s;
}

// ---- main fused kernel (d-split x3: 1536 blocks = 6 waves/SIMD) ------------
// Spart[z][n,m] = sum_{d in third z} text[n,d]*rcp(1+exp2(kw2t[n,d]+kw3v[m,d]*Ct[n,m]))
#define DCH    64
#define DRANGE 256
#define MLDW   68

__global__ __launch_bounds__(256) void main_kernel(
    const float* __restrict__ text, const float* __restrict__ kw2t,
    const float* __restrict__ kw3v, const float* __restrict__ Ct,
    float* __restrict__ Spart)
{
  __shared__ float ts[16][MLDW];
  __shared__ float w2s[16][MLDW];
  __shared__ float w3s[32][MLDW];

  const int tid = threadIdx.x;
  const int nl = tid >> 4;
  const int ml = tid & 15;
  const int n0 = blockIdx.y * 16;
  const int m0 = blockIdx.x * 32;
  const int z  = blockIdx.z;
  const int n  = n0 + nl;
  const int mA = m0 + ml, mB = mA + 16;
  const int dbase = z * DRANGE;

  const float cA = Ct[(size_t)n * MM + mA];
  const float cB = Ct[(size_t)n * MM + mB];

  float4 aA = {0.f, 0.f, 0.f, 0.f};
  float4 aB = {0.f, 0.f, 0.f, 0.f};

  const int srow = tid >> 4;
  const int sc4  = (tid & 15) << 2;

  for (int dc = 0; dc < DRANGE; dc += DCH) {
    const int d0 = dbase + dc;
    *(float4*)&ts[srow][sc4]       = *(const float4*)&text[(size_t)(n0 + srow) * DD + d0 + sc4];
    *(float4*)&w2s[srow][sc4]      = *(const float4*)&kw2t[(size_t)(n0 + srow) * DD + d0 + sc4];
    *(float4*)&w3s[srow][sc4]      = *(const float4*)&kw3v[(size_t)(m0 + srow) * DD + d0 + sc4];
    *(float4*)&w3s[srow + 16][sc4] = *(const float4*)&kw3v[(size_t)(m0 + 16 + srow) * DD + d0 + sc4];
    __syncthreads();

    #pragma unroll 4
    for (int j = 0; j < DCH; j += 4) {
      const float4 tv  = *(const float4*)&ts[nl][j];
      const float4 w2  = *(const float4*)&w2s[nl][j];
      const float4 w3A = *(const float4*)&w3s[ml][j];
      const float4 w3B = *(const float4*)&w3s[ml + 16][j];
      aA.x = fmaf(tv.x, frcp(fexp(fmaf(w3A.x, cA, w2.x)) + 1.0f), aA.x);
      aA.y = fmaf(tv.y, frcp(fexp(fmaf(w3A.y, cA, w2.y)) + 1.0f), aA.y);
      aA.z = fmaf(tv.z, frcp(fexp(fmaf(w3A.z, cA, w2.z)) + 1.0f), aA.z);
      aA.w = fmaf(tv.w, frcp(fexp(fmaf(w3A.w, cA, w2.w)) + 1.0f), aA.w);
      aB.x = fmaf(tv.x, frcp(fexp(fmaf(w3B.x, cB, w2.x)) + 1.0f), aB.x);
      aB.y = fmaf(tv.y, frcp(fexp(fmaf(w3B.y, cB, w2.y)) + 1.0f), aB.y);
      aB.z = fmaf(tv.z, frcp(fexp(fmaf(w3B.z, cB, w2.z)) + 1.0f), aB.z);
      aB.w = fmaf(tv.w, frcp(fexp(fmaf(w3B.w, cB, w2.w)) + 1.0f), aB.w);
    }
    __syncthreads();
  }

  float* Sp = Spart + (size_t)z * NN * MM + (size_t)n * MM;
  Sp[mA] = (aA.x + aA.y) + (aA.z + aA.w);
  Sp[mB] = (aB.x + aB.y) + (aB.z + aB.w);
}

// out[n,m] = T[n] - 2*(S0+S1+S2)
__global__ __launch_bounds__(256) void combine_kernel(
    const float* __restrict__ Spart, const float* __restrict__ T,
    float* __restrict__ out)
{
  const size_t i = ((size_t)blockIdx.x * 256 + threadIdx.x) * 4;
  const size_t S = (size_t)NN * MM;
  const int n = (int)(i >> 9);
  const float Tn = T[n];
  const float4 s0 = *(const float4*)&Spart[i];
  const float4 s1 = *(const float4*)&Spart[S + i];
  const float4 s2 = *(const float4*)&Spart[2 * S + i];
  float4 o;
  o.x = Tn - 2.0f * (s0.x + s1.x + s2.x);
  o.y = Tn - 2.0f * (s0.y + s1.y + s2.y);
  o.z = Tn - 2.0f * (s0.z + s1.z + s2.z);
  o.w = Tn - 2.0f * (s0.w + s1.w + s2.w);
  *(float4*)&out[i] = o;
}

// ---- launcher --------------------------------------------------------------
extern "C" void kernel_launch(void* const* d_in, const int* in_sizes, int n_in,
                              void* d_out, int out_size, void* d_ws, size_t ws_size,
                              hipStream_t stream) {
  const float* text   = (const float*)d_in[0];
  const float* visual = (const float*)d_in[1];
  const float* W1     = (const float*)d_in[2];
  const float* W2     = (const float*)d_in[3];
  const float* W3     = (const float*)d_in[4];
  float* out = (float*)d_out;

  // Workspace byte layout (peak 14.25 MB, proven available in R3/R6/R7):
  //   th/tl/vh/vl : f16 hi/lo of text, visual     (4 x 768 KB)
  //   w1t/w2t h,l : f16 hi/lo of W1^T,W2^T [j][k] (4 x 1.125 MB)
  //   w3 h/l      : f16 hi/lo of W3 [j][k]        (2 x 1.125 MB)
  //   Ah/Al       : f16 hi/lo of A                (2 x 768 KB)
  //   kw2t/kw3v   : fp32                          (2 x 1.5 MB)
  //   T           : fp32[512]
  // Overlays (stream-serial, source dead before overwrite):
  //   Q  (2 MB) -> w1th/w1tl        (dead after mfma1)
  //   Ct (1 MB) -> w2th             (dead after mfma1)
  //   Spart (3 MB) -> w2tl+w3h+w3l  (dead after mfma1)
  char* base = (char*)d_ws;
  ushort* th   = (ushort*)(base);
  ushort* tl   = (ushort*)(base + 786432);
  ushort* vh   = (ushort*)(base + 1572864);
  ushort* vl   = (ushort*)(base + 2359296);
  ushort* w1th = (ushort*)(base + 3145728);
  ushort* w1tl = (ushort*)(base + 4325376);
  ushort* w2th = (ushort*)(base + 5505024);
  ushort* w2tl = (ushort*)(base + 6684672);
  ushort* w3h  = (ushort*)(base + 7864320);
  ushort* w3l  = (ushort*)(base + 9043968);
  ushort* Ah   = (ushort*)(base + 10223616);
  ushort* Al   = (ushort*)(base + 11010048);
  float*  kw2t = (float*) (base + 11796480);
  float*  kw3v = (float*) (base + 13369344);
  float*  T    = (float*) (base + 14942208);
  float*  Q     = (float*)(base + 3145728);   // 2 MB over w1t
  float*  Ct    = (float*)(base + 5505024);   // 1 MB over w2th
  float*  Spart = (float*)(base + 6684672);   // 3 MB over w2tl+w3

  hipLaunchKernelGGL(tsum_kernel, dim3(NN), dim3(64), 0, stream, text, T);
  hipLaunchKernelGGL(convert_kernel, dim3(DD * DD / 1024, 1, 3), dim3(256), 0, stream,
                     text, visual, W3, th, tl, vh, vl, w3h, w3l);
  hipLaunchKernelGGL(transpose_kernel, dim3(DD / 32, DD / 32, 2), dim3(256), 0, stream,
                     W1, W2, w1th, w1tl, w2th, w2tl);
  hipLaunchKernelGGL(mfma1_kernel, dim3(DD / 64, NN / 64, 3), dim3(256), 0, stream,
                     th, tl, vh, vl, w1th, w1tl, w2th, w2tl, w3h, w3l,
                     Ah, Al, kw2t, kw3v);
  hipLaunchKernelGGL(mfma2_kernel, dim3(MM / 64, NN / 64, 2), dim3(256), 0, stream,
                     Ah, Al, vh, vl, Q);
  hipLaunchKernelGGL(reducec_kernel, dim3(NN * MM / 1024), dim3(256), 0, stream,
                     Q, Ct);
  hipLaunchKernelGGL(main_kernel, dim3(MM / 32, NN / 16, 3), dim3(256), 0, stream,
                     text, kw2t, kw3v, Ct, Spart);
  hipLaunchKernelGGL(combine_kernel, dim3(NN * MM / 1024), dim3(256), 0, stream,
                     Spart, T, out);
}

// Round 9
// 140.458 us; speedup vs baseline: 1.3044x; 1.0446x over previous
//
#include <hip/hip_runtime.h>

// Problem dims (hard-coded in reference)
#define DD   768
#define NN   512
#define MM   512

#define PRE_K 2.88539008177792681472f   // 2*log2(e)

typedef _Float16 h8 __attribute__((ext_vector_type(8)));  // 8 f16 (4 VGPRs)
typedef __attribute__((ext_vector_type(4))) float f32x4;  // MFMA C/D

__device__ __forceinline__ float fexp(float x) { return __builtin_amdgcn_exp2f(x); }
__device__ __forceinline__ float frcp(float x) { return __builtin_amdgcn_rcpf(x); }
// tanh(x) = 1 - 2/(1 + e^{2x}); saturates correctly via exp2->inf/0 + rcp.
__device__ __forceinline__ float fast_tanh(float x) {
  return 1.0f - 2.0f * frcp(fexp(PRE_K * x) + 1.0f);
}

// fp32 -> f16 hi/lo split (pair covers ~21 mantissa bits)
__device__ __forceinline__ void splitf(float x, ushort& h, ushort& l) {
  const _Float16 hh = (_Float16)x;
  const _Float16 ll = (_Float16)(x - (float)hh);
  h = __builtin_bit_cast(unsigned short, hh);
  l = __builtin_bit_cast(unsigned short, ll);
}

// ---- fused prep: convert text/visual/W3 + transpose-convert W1/W2 ----------
// One launch replaces convert+transpose (R8 lesson: ~6-8us per serial launch).
// blocks [0,384) text, [384,768) visual, [768,1344) W3 (elementwise);
// blocks [1344,1920) W1^T, [1920,2496) W2^T (32x32 LDS transpose tiles).
__global__ __launch_bounds__(256) void prep_kernel(
    const float* __restrict__ text, const float* __restrict__ visual,
    const float* __restrict__ W1, const float* __restrict__ W2,
    const float* __restrict__ W3,
    ushort* __restrict__ th, ushort* __restrict__ tl,
    ushort* __restrict__ vh, ushort* __restrict__ vl,
    ushort* __restrict__ w3h, ushort* __restrict__ w3l,
    ushort* __restrict__ w1th, ushort* __restrict__ w1tl,
    ushort* __restrict__ w2th, ushort* __restrict__ w2tl)
{
  __shared__ float Lt[32][33];
  const int b = blockIdx.x;
  const int t = threadIdx.x;

  if (b < 1344) {
    const float* src; ushort *dh, *dl; size_t off;
    if (b < 384)      { src = text;   dh = th;  dl = tl;  off = (size_t)b * 1024; }
    else if (b < 768) { src = visual; dh = vh;  dl = vl;  off = (size_t)(b - 384) * 1024; }
    else              { src = W3;     dh = w3h; dl = w3l; off = (size_t)(b - 768) * 1024; }
    const size_t i = off + (size_t)t * 4;
    const float4 v = *(const float4*)&src[i];
    ushort4 h, l;
    splitf(v.x, h.x, l.x); splitf(v.y, h.y, l.y);
    splitf(v.z, h.z, l.z); splitf(v.w, h.w, l.w);
    *(ushort4*)&dh[i] = h;
    *(ushort4*)&dl[i] = l;
  } else {
    const int tt = b - 1344;
    const bool second = tt >= 576;
    const int tile = second ? tt - 576 : tt;
    const float* W = second ? W2 : W1;
    ushort* oh = second ? w2th : w1th;
    ushort* ol = second ? w2tl : w1tl;
    const int k0 = (tile / 24) * 32, j0 = (tile % 24) * 32;
    {
      const int k = t >> 3, j4 = (t & 7) * 4;
      const float4 v = *(const float4*)&W[(size_t)(k0 + k) * DD + j0 + j4];
      Lt[j4 + 0][k] = v.x; Lt[j4 + 1][k] = v.y;
      Lt[j4 + 2][k] = v.z; Lt[j4 + 3][k] = v.w;
    }
    __syncthreads();
    {
      const int j = t >> 3, k4 = (t & 7) * 4;
      ushort4 h, l;
      splitf(Lt[j][k4 + 0], h.x, l.x); splitf(Lt[j][k4 + 1], h.y, l.y);
      splitf(Lt[j][k4 + 2], h.z, l.z); splitf(Lt[j][k4 + 3], h.w, l.w);
      *(ushort4*)&oh[(size_t)(j0 + j) * DD + k0 + k4] = h;
      *(ushort4*)&ol[(size_t)(j0 + j) * DD + k0 + k4] = l;
    }
  }
}

// ---- staged-LDS MFMA GEMM core (proven in R8: canonical global->LDS->frag) -
#define BK   32
#define LROW 40   // padded LDS row stride (f16): 2-way banks, 16B-aligned

__device__ __forceinline__ void gemm_core(
    const ushort* __restrict__ Ahg, const ushort* __restrict__ Alg,
    const ushort* __restrict__ Bhg, const ushort* __restrict__ Blg,
    int i0, int j0, int k0, int nsteps, f32x4* acc)
{
  __shared__ ushort As[2][2][64 * LROW];   // [buf][hi/lo][row*LROW+k]
  __shared__ ushort Bs[2][2][64 * LROW];

  const int tid  = threadIdx.x;
  const int row  = tid >> 2;            // 0..63 staging row
  const int ks8  = (tid & 3) * 8;       // 0,8,16,24 (f16)
  const size_t ga = (size_t)(i0 + row) * DD + k0 + ks8;
  const size_t gb = (size_t)(j0 + row) * DD + k0 + ks8;
  const int ldsw = row * LROW + ks8;

  const int lane = tid & 63, wave = tid >> 6;
  const int r15 = lane & 15, quad = lane >> 4;
  const int fa = (wave * 16 + r15) * LROW + quad * 8;   // A frag offset
  const int fb = r15 * LROW + quad * 8;                 // B frag base

  // prefetch step 0
  h8 pah = *(const h8*)(Ahg + ga);
  h8 pal = *(const h8*)(Alg + ga);
  h8 pbh = *(const h8*)(Bhg + gb);
  h8 pbl = *(const h8*)(Blg + gb);

  int p = 0;
  *(h8*)&As[0][0][ldsw] = pah; *(h8*)&As[0][1][ldsw] = pal;
  *(h8*)&Bs[0][0][ldsw] = pbh; *(h8*)&Bs[0][1][ldsw] = pbl;
  __syncthreads();

  for (int s = 0; s < nsteps; ++s) {
    const bool more = (s + 1 < nsteps);
    if (more) {  // issue next chunk's globals; MFMA below hides latency
      pah = *(const h8*)(Ahg + ga + (s + 1) * BK);
      pal = *(const h8*)(Alg + ga + (s + 1) * BK);
      pbh = *(const h8*)(Bhg + gb + (s + 1) * BK);
      pbl = *(const h8*)(Blg + gb + (s + 1) * BK);
    }
    const h8 a_h = *(const h8*)&As[p][0][fa];
    const h8 a_l = *(const h8*)&As[p][1][fa];
    h8 b_h[4], b_l[4];
    #pragma unroll
    for (int c = 0; c < 4; ++c) {
      b_h[c] = *(const h8*)&Bs[p][0][fb + c * 16 * LROW];
      b_l[c] = *(const h8*)&Bs[p][1][fb + c * 16 * LROW];
    }
    #pragma unroll
    for (int c = 0; c < 4; ++c)
      acc[c] = __builtin_amdgcn_mfma_f32_16x16x32_f16(a_h, b_h[c], acc[c], 0, 0, 0);
    #pragma unroll
    for (int c = 0; c < 4; ++c)
      acc[c] = __builtin_amdgcn_mfma_f32_16x16x32_f16(a_h, b_l[c], acc[c], 0, 0, 0);
    #pragma unroll
    for (int c = 0; c < 4; ++c)
      acc[c] = __builtin_amdgcn_mfma_f32_16x16x32_f16(a_l, b_h[c], acc[c], 0, 0, 0);
    if (more) {
      const int q = p ^ 1;
      *(h8*)&As[q][0][ldsw] = pah; *(h8*)&As[q][1][ldsw] = pal;
      *(h8*)&Bs[q][0][ldsw] = pbh; *(h8*)&Bs[q][1][ldsw] = pbl;
    }
    __syncthreads();
    p ^= 1;
  }
}

// z=0: A=text@W1 -> Ah/Al(f16)  z=1: kw2t=PRE_K*text@W2  z=2: kw3v=PRE_K*visual@W3^T
__global__ __launch_bounds__(256) void mfma1_kernel(
    const ushort* __restrict__ th, const ushort* __restrict__ tl,
    const ushort* __restrict__ vh, const ushort* __restrict__ vl,
    const ushort* __restrict__ w1th, const ushort* __restrict__ w1tl,
    const ushort* __restrict__ w2th, const ushort* __restrict__ w2tl,
    const ushort* __restrict__ w3h, const ushort* __restrict__ w3l,
    ushort* __restrict__ Ah, ushort* __restrict__ Al,
    float* __restrict__ kw2t, float* __restrict__ kw3v)
{
  const int z  = blockIdx.z;
  const int j0 = blockIdx.x * 64;
  const int i0 = blockIdx.y * 64;
  const ushort *Arh, *Arl, *Brh, *Brl;
  if (z == 0)      { Arh = th; Arl = tl; Brh = w1th; Brl = w1tl; }
  else if (z == 1) { Arh = th; Arl = tl; Brh = w2th; Brl = w2tl; }
  else             { Arh = vh; Arl = vl; Brh = w3h;  Brl = w3l;  }

  f32x4 acc[4];
  #pragma unroll
  for (int c = 0; c < 4; ++c) acc[c] = (f32x4){0.f, 0.f, 0.f, 0.f};
  gemm_core(Arh, Arl, Brh, Brl, i0, j0, 0, DD / BK, acc);

  const int lane = threadIdx.x & 63, wave = threadIdx.x >> 6;
  const int r15 = lane & 15, quad = lane >> 4;
  // C/D layout: col=lane&15 (B row j), row=quad*4+reg (A row i)
  if (z == 0) {
    #pragma unroll
    for (int c = 0; c < 4; ++c)
      #pragma unroll
      for (int r = 0; r < 4; ++r) {
        const size_t o = (size_t)(i0 + wave * 16 + quad * 4 + r) * DD + j0 + c * 16 + r15;
        splitf(acc[c][r], Ah[o], Al[o]);
      }
  } else {
    float* Out = (z == 1) ? kw2t : kw3v;
    #pragma unroll
    for (int c = 0; c < 4; ++c)
      #pragma unroll
      for (int r = 0; r < 4; ++r)
        Out[(size_t)(i0 + wave * 16 + quad * 4 + r) * DD + j0 + c * 16 + r15] =
            acc[c][r] * PRE_K;
  }
}

// Q[z] = A @ visual^T over K quarter z.  grid (8,8,4) = 256 blocks (full GPU;
// R8's 128 blocks left half the CUs idle).
__global__ __launch_bounds__(256) void mfma2_kernel(
    const ushort* __restrict__ Ah, const ushort* __restrict__ Al,
    const ushort* __restrict__ vh, const ushort* __restrict__ vl,
    float* __restrict__ Q)
{
  const int z  = blockIdx.z;
  const int j0 = blockIdx.x * 64;
  const int i0 = blockIdx.y * 64;

  f32x4 acc[4];
  #pragma unroll
  for (int c = 0; c < 4; ++c) acc[c] = (f32x4){0.f, 0.f, 0.f, 0.f};
  gemm_core(Ah, Al, vh, vl, i0, j0, z * (DD / 4), (DD / 4) / BK, acc);

  const int lane = threadIdx.x & 63, wave = threadIdx.x >> 6;
  const int r15 = lane & 15, quad = lane >> 4;
  float* Out = Q + (size_t)z * NN * MM;
  #pragma unroll
  for (int c = 0; c < 4; ++c)
    #pragma unroll
    for (int r = 0; r < 4; ++r)
      Out[(size_t)(i0 + wave * 16 + quad * 4 + r) * MM + j0 + c * 16 + r15] = acc[c][r];
}

// ---- main fused kernel (d-split x3; prologue absorbs reducec) --------------
// cval = tanh(sum_z Q[z][n,m]);
// Spart[z][n,m] = sum_{d in third z} text[n,d]*rcp(1+exp2(kw2t[n,d]+kw3v[m,d]*cval))
#define DCH    64
#define DRANGE 256
#define MLDW   68

__global__ __launch_bounds__(256) void main_kernel(
    const float* __restrict__ text, const float* __restrict__ kw2t,
    const float* __restrict__ kw3v, const float* __restrict__ Q,
    float* __restrict__ Spart)
{
  __shared__ float ts[16][MLDW];
  __shared__ float w2s[16][MLDW];
  __shared__ float w3s[32][MLDW];

  const int tid = threadIdx.x;
  const int nl = tid >> 4;
  const int ml = tid & 15;
  const int n0 = blockIdx.y * 16;
  const int m0 = blockIdx.x * 32;
  const int z  = blockIdx.z;
  const int n  = n0 + nl;
  const int mA = m0 + ml, mB = mA + 16;
  const int dbase = z * DRANGE;

  float cA = 0.f, cB = 0.f;
  #pragma unroll
  for (int zz = 0; zz < 4; ++zz) {
    const float* q = Q + (size_t)zz * NN * MM + (size_t)n * MM;
    cA += q[mA]; cB += q[mB];
  }
  cA = fast_tanh(cA); cB = fast_tanh(cB);

  float4 aA = {0.f, 0.f, 0.f, 0.f};
  float4 aB = {0.f, 0.f, 0.f, 0.f};

  const int srow = tid >> 4;
  const int sc4  = (tid & 15) << 2;

  for (int dc = 0; dc < DRANGE; dc += DCH) {
    const int d0 = dbase + dc;
    *(float4*)&ts[srow][sc4]       = *(const float4*)&text[(size_t)(n0 + srow) * DD + d0 + sc4];
    *(float4*)&w2s[srow][sc4]      = *(const float4*)&kw2t[(size_t)(n0 + srow) * DD + d0 + sc4];
    *(float4*)&w3s[srow][sc4]      = *(const float4*)&kw3v[(size_t)(m0 + srow) * DD + d0 + sc4];
    *(float4*)&w3s[srow + 16][sc4] = *(const float4*)&kw3v[(size_t)(m0 + 16 + srow) * DD + d0 + sc4];
    __syncthreads();

    #pragma unroll 4
    for (int j = 0; j < DCH; j += 4) {
      const float4 tv  = *(const float4*)&ts[nl][j];
      const float4 w2  = *(const float4*)&w2s[nl][j];
      const float4 w3A = *(const float4*)&w3s[ml][j];
      const float4 w3B = *(const float4*)&w3s[ml + 16][j];
      aA.x = fmaf(tv.x, frcp(fexp(fmaf(w3A.x, cA, w2.x)) + 1.0f), aA.x);
      aA.y = fmaf(tv.y, frcp(fexp(fmaf(w3A.y, cA, w2.y)) + 1.0f), aA.y);
      aA.z = fmaf(tv.z, frcp(fexp(fmaf(w3A.z, cA, w2.z)) + 1.0f), aA.z);
      aA.w = fmaf(tv.w, frcp(fexp(fmaf(w3A.w, cA, w2.w)) + 1.0f), aA.w);
      aB.x = fmaf(tv.x, frcp(fexp(fmaf(w3B.x, cB, w2.x)) + 1.0f), aB.x);
      aB.y = fmaf(tv.y, frcp(fexp(fmaf(w3B.y, cB, w2.y)) + 1.0f), aB.y);
      aB.z = fmaf(tv.z, frcp(fexp(fmaf(w3B.z, cB, w2.z)) + 1.0f), aB.z);
      aB.w = fmaf(tv.w, frcp(fexp(fmaf(w3B.w, cB, w2.w)) + 1.0f), aB.w);
    }
    __syncthreads();
  }

  float* Sp = Spart + (size_t)z * NN * MM + (size_t)n * MM;
  Sp[mA] = (aA.x + aA.y) + (aA.z + aA.w);
  Sp[mB] = (aB.x + aB.y) + (aB.z + aB.w);
}

// out[n,m] = T[n] - 2*(S0+S1+S2); T computed in-block (absorbs tsum).
// Block b handles rows n0=2b, 2b+1 (1024 outputs).
__global__ __launch_bounds__(256) void combine_kernel(
    const float* __restrict__ Spart, const float* __restrict__ text,
    float* __restrict__ out)
{
  __shared__ float red[256];
  __shared__ float Tsh[2];
  const int b = blockIdx.x, t = threadIdx.x;
  const int n0 = b * 2;
  const int half = t >> 7;          // which row this thread reduces
  const int lt = t & 127;

  const float* tr = text + (size_t)(n0 + half) * DD;
  float s = 0.f;
  #pragma unroll
  for (int i = 0; i < DD / 128; ++i) s += tr[lt + i * 128];
  red[t] = s;
  __syncthreads();
  #pragma unroll
  for (int st = 64; st > 0; st >>= 1) {
    if (lt < st) red[t] += red[t + st];
    __syncthreads();
  }
  if (lt == 0) Tsh[half] = red[t];
  __syncthreads();

  const size_t i = (size_t)b * 1024 + (size_t)t * 4;
  const size_t S = (size_t)NN * MM;
  const float Tn = Tsh[half];
  const float4 s0 = *(const float4*)&Spart[i];
  const float4 s1 = *(const float4*)&Spart[S + i];
  const float4 s2 = *(const float4*)&Spart[2 * S + i];
  float4 o;
  o.x = Tn - 2.0f * (s0.x + s1.x + s2.x);
  o.y = Tn - 2.0f * (s0.y + s1.y + s2.y);
  o.z = Tn - 2.0f * (s0.z + s1.z + s2.z);
  o.w = Tn - 2.0f * (s0.w + s1.w + s2.w);
  *(float4*)&out[i] = o;
}

// ---- launcher --------------------------------------------------------------
extern "C" void kernel_launch(void* const* d_in, const int* in_sizes, int n_in,
                              void* d_out, int out_size, void* d_ws, size_t ws_size,
                              hipStream_t stream) {
  const float* text   = (const float*)d_in[0];
  const float* visual = (const float*)d_in[1];
  const float* W1     = (const float*)d_in[2];
  const float* W2     = (const float*)d_in[3];
  const float* W3     = (const float*)d_in[4];
  float* out = (float*)d_out;

  // Workspace byte layout (peak 14.25 MB, proven available):
  //   th/tl/vh/vl : f16 hi/lo of text, visual     (4 x 768 KB)
  //   w1t/w2t h,l : f16 hi/lo of W1^T,W2^T [j][k] (4 x 1.125 MB)
  //   w3 h/l      : f16 hi/lo of W3 [j][k]        (2 x 1.125 MB)
  //   Ah/Al       : f16 hi/lo of A                (2 x 768 KB)
  //   kw2t/kw3v   : fp32                          (2 x 1.5 MB)
  // Overlays (stream-serial; sources dead before overwrite):
  //   Q  (4 MB) -> w1th..w2tl       (dead after mfma1; mfma2 writes Q)
  //   Spart (3 MB) -> w3h+w3l+Ah    (w3 dead after mfma1; Ah read by mfma2
  //                                  which completes before main writes Spart)
  char* base = (char*)d_ws;
  ushort* th   = (ushort*)(base);
  ushort* tl   = (ushort*)(base + 786432);
  ushort* vh   = (ushort*)(base + 1572864);
  ushort* vl   = (ushort*)(base + 2359296);
  ushort* w1th = (ushort*)(base + 3145728);
  ushort* w1tl = (ushort*)(base + 4325376);
  ushort* w2th = (ushort*)(base + 5505024);
  ushort* w2tl = (ushort*)(base + 6684672);
  ushort* w3h  = (ushort*)(base + 7864320);
  ushort* w3l  = (ushort*)(base + 9043968);
  ushort* Ah   = (ushort*)(base + 10223616);
  ushort* Al   = (ushort*)(base + 11010048);
  float*  kw2t = (float*) (base + 11796480);
  float*  kw3v = (float*) (base + 13369344);
  float*  Q     = (float*)(base + 3145728);   // 4 MB over w1t/w2t
  float*  Spart = (float*)(base + 7864320);   // 3 MB over w3 + Ah

  hipLaunchKernelGGL(prep_kernel, dim3(2496), dim3(256), 0, stream,
                     text, visual, W1, W2, W3,
                     th, tl, vh, vl, w3h, w3l, w1th, w1tl, w2th, w2tl);
  hipLaunchKernelGGL(mfma1_kernel, dim3(DD / 64, NN / 64, 3), dim3(256), 0, stream,
                     th, tl, vh, vl, w1th, w1tl, w2th, w2tl, w3h, w3l,
                     Ah, Al, kw2t, kw3v);
  hipLaunchKernelGGL(mfma2_kernel, dim3(MM / 64, NN / 64, 4), dim3(256), 0, stream,
                     Ah, Al, vh, vl, Q);
  hipLaunchKernelGGL(main_kernel, dim3(MM / 32, NN / 16, 3), dim3(256), 0, stream,
                     text, kw2t, kw3v, Q, Spart);
  hipLaunchKernelGGL(combine_kernel, dim3(NN * MM / 1024), dim3(256), 0, stream,
                     Spart, text, out);
}